// Round 6
// baseline (516.622 us; speedup 1.0000x reference)
//
#include <hip/hip_runtime.h>
#include <stdint.h>

// ---------------------------------------------------------------------------
// Social LSTM model, bf16x3 MFMA everywhere.
//   enc:  LSTM(2->64), T=50, 2176 blocks x 4 waves, 16 seqs/block.
//         Whh register-resident B-frags (hi/lo). Ping-pong h LDS planes
//         => 1 barrier/step.
//   pool: masked max over valid neighbours, concat -> h0 [2048,128]
//   dec:  LSTMCell(128->128), 30 steps. 256 blocks x 8 waves, 8 seqs/block.
//         B register-resident (128 VGPR/wave, loaded once). Gates cross
//         waves via padded LDS; cell phase wave w <-> seq w.
// Pointwise: shared-rcp sigmoid/tanh algebra (7 transcendentals/cell).
// ---------------------------------------------------------------------------

#define T_SEQ 50
#define PRED_STEPS 30
#define NMAX 16

typedef float v2f __attribute__((ext_vector_type(2)));
typedef float v4f __attribute__((ext_vector_type(4)));
typedef short v8s __attribute__((ext_vector_type(8)));

// ws layout (float offsets)
static constexpr size_t OFF_AEMB  = 0;          // 2048*64
static constexpr size_t OFF_NENC  = 131072;     // 32768*64
static constexpr size_t OFF_H0    = 2228224;    // 2048*128
static constexpr size_t OFF_PACKA = 2490368;    // 64 KB bf16 B-frags (agent)
static constexpr size_t OFF_PACKN = 2507520;    // 64 KB bf16 B-frags (neigh)
static constexpr size_t OFF_WDP   = 2524672;    // 256 KB dec bf16 B-frags
static constexpr size_t OFF_WDB   = 2590208;    // 512 fused dec bias

__device__ __forceinline__ float frcp(float x) { return __builtin_amdgcn_rcpf(x); }
__device__ __forceinline__ unsigned bf16rne(float f) {
  unsigned u = __float_as_uint(f);
  u += 0x7fff + ((u >> 16) & 1);
  return u >> 16;
}
__device__ __forceinline__ float bf16tof(unsigned h) { return __uint_as_float(h << 16); }
__device__ __forceinline__ v4f mfma16(v8s a, v8s b, v4f c) {
  return __builtin_amdgcn_mfma_f32_16x16x32_bf16(a, b, c, 0, 0, 0);
}

// Shared-rcp LSTM cell update (7 transcendentals).
__device__ __forceinline__ float cell_update(float iv, float fv, float gv,
                                             float ov, float& cref) {
  float ef = __expf(-fv);
  float ei = __expf(-iv);
  float eg = __expf(-2.f * gv);
  float t1 = (1.f + ei) * (1.f + eg);
  float rD = frcp((1.f + ef) * t1);
  float sf = t1 * rD;
  float u  = (1.f - eg) * ((1.f + ef) * rD);
  float cn = fmaf(sf, cref, u);
  cref = cn;
  float eo = __expf(-ov);
  float ec = __expf(fminf(-2.f * cn, 41.5f));
  return (1.f - ec) * frcp((1.f + eo) * (1.f + ec));
}

// ---------------------------------------------------------------------------
// Prep: encoder Whh as MFMA B-fragments, bf16 hi/lo split (RNE).
// ---------------------------------------------------------------------------
__global__ void prep_encpack(const float* __restrict__ Whh_a, const float* __restrict__ Whh_n,
                             uint4* __restrict__ packA, uint4* __restrict__ packN) {
  const int which = blockIdx.x >> 4;
  const int idx = (blockIdx.x & 15) * 256 + threadIdx.x;  // 0..4095
  const float* Whh = which ? Whh_n : Whh_a;
  uint4* dst = which ? packN : packA;
  const int lane = idx & 63, c = idx >> 6;
  const int p = c & 1, kh = (c >> 1) & 1, g = (c >> 2) & 3, w = (c >> 4) & 3;
  const int row = g * 64 + 16 * w + (lane & 15);
  const int kb = kh * 32 + (lane >> 4) * 8;
  unsigned us[8];
#pragma unroll
  for (int e = 0; e < 8; ++e) {
    float W = Whh[row * 64 + kb + e];
    unsigned hi = bf16rne(W);
    us[e] = p ? bf16rne(W - bf16tof(hi)) : hi;
  }
  uint4 o;
  o.x = us[0] | (us[1] << 16);
  o.y = us[2] | (us[3] << 16);
  o.z = us[4] | (us[5] << 16);
  o.w = us[6] | (us[7] << 16);
  dst[c * 64 + lane] = o;
}

// ---------------------------------------------------------------------------
// Prep: decoder fused W = Wih_d + Whh_d as B-frags (bf16 hi/lo).
// chunk c = (g<<6)|(uhf<<5)|(ut<<3)|(kh<<1)|p ; 256 chunks x 1 KB.
// lane: unit j = uhf*64+ut*16+(l&15), k = kh*32+(l>>4)*8+e, row = g*128+j.
// ---------------------------------------------------------------------------
__global__ void prep_decpack(const float* __restrict__ Wih, const float* __restrict__ Whh,
                             const float* __restrict__ bih, const float* __restrict__ bhh,
                             uint4* __restrict__ dst, float* __restrict__ bd) {
  const int idx = blockIdx.x * 256 + threadIdx.x;  // 0..16383
  const int lane = idx & 63, c = idx >> 6;
  const int p = c & 1, kh = (c >> 1) & 3, ut = (c >> 3) & 3, uhf = (c >> 5) & 1, g = (c >> 6) & 3;
  const int j = uhf * 64 + ut * 16 + (lane & 15);
  const int row = g * 128 + j;
  const int kb = kh * 32 + (lane >> 4) * 8;
  unsigned us[8];
#pragma unroll
  for (int e = 0; e < 8; ++e) {
    float W = Wih[row * 128 + kb + e] + Whh[row * 128 + kb + e];
    unsigned hi = bf16rne(W);
    us[e] = p ? bf16rne(W - bf16tof(hi)) : hi;
  }
  uint4 o;
  o.x = us[0] | (us[1] << 16);
  o.y = us[2] | (us[3] << 16);
  o.z = us[4] | (us[5] << 16);
  o.w = us[6] | (us[7] << 16);
  dst[c * 64 + lane] = o;
  if (blockIdx.x < 2) {
    int i = blockIdx.x * 256 + threadIdx.x;  // 0..511
    bd[i] = bih[i] + bhh[i];
  }
}

// ---------------------------------------------------------------------------
// Encoder. Blocks [0,2048) neighbour, [2048,2176) agent; 256 thr = 4 waves.
// Ping-pong h planes: buf b at halfword base b*2304; hi [+0,+1152),
// lo [+1152,+2304); row stride 72 halfwords (16B-aligned b128 reads).
// One barrier per timestep.
// ---------------------------------------------------------------------------
__global__ __launch_bounds__(256, 4) void enc_mfma_kernel(
    const float* __restrict__ xA, const float* __restrict__ xN,
    const v8s* __restrict__ packA, const v8s* __restrict__ packN,
    const float* __restrict__ Wih_a, const float* __restrict__ bih_a, const float* __restrict__ bhh_a,
    const float* __restrict__ Wih_n, const float* __restrict__ bih_n, const float* __restrict__ bhh_n,
    float* __restrict__ outA, float* __restrict__ outN) {
  __shared__ unsigned short hph[4608];  // 2 ping-pong buffers
  __shared__ float xst[1600];
  const int tid = threadIdx.x, lane = tid & 63, wv = tid >> 6;
  const int nb = blockIdx.x;
  const bool isA = nb >= 2048;
  const float* xsrc = isA ? xA : xN;
  const v8s* pk = isA ? packA : packN;
  const float* Wih = isA ? Wih_a : Wih_n;
  const float* bih = isA ? bih_a : bih_n;
  const float* bhh = isA ? bhh_a : bhh_n;
  float* outp = isA ? outA : outN;
  const int s0 = (isA ? nb - 2048 : nb) * 16;

  // register-resident B fragments: [gate][khalf][hi/lo]
  v8s B[4][2][2];
#pragma unroll
  for (int g = 0; g < 4; ++g)
#pragma unroll
    for (int kh = 0; kh < 2; ++kh)
#pragma unroll
      for (int p = 0; p < 2; ++p)
        B[g][kh][p] = pk[((((wv * 4 + g) * 2 + kh) * 2 + p) << 6) + lane];

  const int jc = lane & 15, qc = lane >> 4;  // C roles: unit col, seq quad
  float wi0[4], wi1[4], bs[4];
#pragma unroll
  for (int g = 0; g < 4; ++g) {
    int n = g * 64 + 16 * wv + jc;
    wi0[g] = Wih[n * 2 + 0];
    wi1[g] = Wih[n * 2 + 1];
    bs[g] = bih[n] + bhh[n];
  }

  // stage x (1600 floats) + zero buf0 (1152 dwords = 2304 halfwords)
  {
    const float4* xb = (const float4*)(xsrc + (size_t)s0 * 100);
    for (int i = tid; i < 400; i += 256) ((float4*)xst)[i] = xb[i];
    for (int i = tid; i < 1152; i += 256) ((unsigned*)hph)[i] = 0;
  }
  __syncthreads();

  const int ms = lane & 15, ks = lane >> 4;  // A roles: seq row, k-quad
  float cst[4] = {0.f, 0.f, 0.f, 0.f};
  float h[4];

  for (int t = 0; t < T_SEQ; ++t) {
    const int rb = (t & 1) * 2304;          // read buffer base
    const int wb = 2304 - rb;               // write buffer base
    v8s Ahi[2], Alo[2];
#pragma unroll
    for (int kh = 0; kh < 2; ++kh) {
      Ahi[kh] = *(const __shared__ v8s*)&hph[rb + ms * 72 + kh * 32 + ks * 8];
      Alo[kh] = *(const __shared__ v8s*)&hph[rb + 1152 + ms * 72 + kh * 32 + ks * 8];
    }

    // acc init: exact fp32 input projection + bias
    v4f a4[4];
#pragma unroll
    for (int r = 0; r < 4; ++r) {
      v2f xv = *(const __shared__ v2f*)&xst[(qc * 4 + r) * 100 + 2 * t];
#pragma unroll
      for (int g = 0; g < 4; ++g)
        a4[g][r] = fmaf(wi1[g], xv.y, fmaf(wi0[g], xv.x, bs[g]));
    }

    // h @ Whh^T via bf16x3 MFMA
#pragma unroll
    for (int g = 0; g < 4; ++g)
#pragma unroll
      for (int kh = 0; kh < 2; ++kh) {
        a4[g] = mfma16(Ahi[kh], B[g][kh][0], a4[g]);
        a4[g] = mfma16(Ahi[kh], B[g][kh][1], a4[g]);
        a4[g] = mfma16(Alo[kh], B[g][kh][0], a4[g]);
      }

    // pointwise + truncation-split b16 stores into the OTHER buffer
#pragma unroll
    for (int r = 0; r < 4; ++r) {
      h[r] = cell_update(a4[0][r], a4[1][r], a4[2][r], a4[3][r], cst[r]);
      unsigned uu = __float_as_uint(h[r]);
      float hif = __uint_as_float(uu & 0xffff0000u);
      float lof = h[r] - hif;
      int ha = wb + (qc * 4 + r) * 72 + 16 * wv + jc;
      hph[ha] = (unsigned short)(uu >> 16);
      hph[1152 + ha] = (unsigned short)(__float_as_uint(lof) >> 16);
    }
    __syncthreads();  // single barrier: writes visible for next-step reads
  }

#pragma unroll
  for (int r = 0; r < 4; ++r)
    outp[(size_t)(s0 + qc * 4 + r) * 64 + 16 * wv + jc] = h[r];
}

// Masked neighbour max-pool + concat -> h0 [B,128]
__global__ void hmax_kernel(const float* __restrict__ aemb, const float* __restrict__ nenc,
                            const int* __restrict__ cnts, float* __restrict__ h0) {
  const int idx = blockIdx.x * 256 + threadIdx.x;  // 2048*64
  const int b = idx >> 6, j = idx & 63;
  h0[(size_t)b * 128 + j] = aemb[(size_t)b * 64 + j];
  const int cnt = cnts[b];
  float m = -1e30f;
  for (int n = 0; n < cnt; ++n) m = fmaxf(m, nenc[((size_t)(b * NMAX + n)) * 64 + j]);
  h0[(size_t)b * 128 + 64 + j] = (cnt > 0) ? m : 0.f;
}

// ---------------------------------------------------------------------------
// Decoder MFMA v2. 256 blocks x 512 thr (8 waves), 8 seqs/block.
// Wave wv: gate g = wv&3, unit-half uhf = wv>>2 -> 4 col-tiles of 16 units.
// B register-resident (32 v8s = 128 VGPR), loaded ONCE before the t-loop.
// Gates cross waves via gbuf[4][8][132] (padded, conflict-free).
// Cell phase: wave w <-> seq w, lane handles units {2l, 2l+1}.
// h planes: halfwords, row stride 136; hi [0,2176), lo [2176,4352);
// rows 8..15 zeroed once (A rows 8-15 unused garbage-free).
// ---------------------------------------------------------------------------
__global__ __launch_bounds__(512, 2) void dec_mfma_kernel(
    const v8s* __restrict__ pkd, const float* __restrict__ bd,
    const float* __restrict__ h0, const float* __restrict__ Wpos,
    const float* __restrict__ bpos, float* __restrict__ out) {
  __shared__ unsigned short hph[4352];
  __shared__ float gbuf[4][8][132];
  const int tid = threadIdx.x, lane = tid & 63, wv = tid >> 6;
  const int jc = lane & 15, qc = lane >> 4;
  const int g = wv & 3, uhf = wv >> 2;
  const int s0 = blockIdx.x * 8;

  // register-resident B fragments: [utile][kh][hi/lo]
  v8s B[4][4][2];
#pragma unroll
  for (int ut = 0; ut < 4; ++ut)
#pragma unroll
    for (int kh = 0; kh < 4; ++kh)
#pragma unroll
      for (int p = 0; p < 2; ++p) {
        int c = (g << 6) | (uhf << 5) | (ut << 3) | (kh << 1) | p;
        B[ut][kh][p] = pkd[(c << 6) + lane];
      }
  float bs[4];
#pragma unroll
  for (int ut = 0; ut < 4; ++ut)
    bs[ut] = bd[g * 128 + uhf * 64 + ut * 16 + jc];

  // per-thread cell/pred constants: seq = wv, units u0=2*lane, u0+1
  const int u0 = 2 * lane;
  const float wpA0 = Wpos[u0], wpA1 = Wpos[u0 + 1];
  const float wpB0 = Wpos[128 + u0], wpB1 = Wpos[128 + u0 + 1];
  const float bp0 = bpos[0], bp1 = bpos[1];

  // stage h0 (rows 0..7) + zero rows 8..15
  for (int i = tid; i < 2048; i += 512) {
    int row = i >> 7, unit = i & 127;
    unsigned hiw = 0, low = 0;
    if (row < 8) {
      float v = h0[(size_t)(s0 + row) * 128 + unit];
      unsigned u = __float_as_uint(v);
      float hif = __uint_as_float(u & 0xffff0000u);
      float lof = v - hif;
      hiw = u >> 16;
      low = __float_as_uint(lof) >> 16;
    }
    hph[row * 136 + unit] = (unsigned short)hiw;
    hph[2176 + row * 136 + unit] = (unsigned short)low;
  }
  float cA = 0.f, cB = 0.f;
  __syncthreads();

  for (int t = 0; t < PRED_STEPS; ++t) {
    // A fragments (rows = seqs, rows 8-15 zero)
    v8s Ahi[4], Alo[4];
#pragma unroll
    for (int kh = 0; kh < 4; ++kh) {
      Ahi[kh] = *(const __shared__ v8s*)&hph[jc * 136 + kh * 32 + qc * 8];
      Alo[kh] = *(const __shared__ v8s*)&hph[2176 + jc * 136 + kh * 32 + qc * 8];
    }

    // gates for this wave's 4 col-tiles
    v4f acc[4];
#pragma unroll
    for (int ut = 0; ut < 4; ++ut)
      acc[ut] = (v4f){bs[ut], bs[ut], bs[ut], bs[ut]};
#pragma unroll
    for (int ut = 0; ut < 4; ++ut)
#pragma unroll
      for (int kh = 0; kh < 4; ++kh) {
        acc[ut] = mfma16(Ahi[kh], B[ut][kh][0], acc[ut]);
        acc[ut] = mfma16(Ahi[kh], B[ut][kh][1], acc[ut]);
        acc[ut] = mfma16(Alo[kh], B[ut][kh][0], acc[ut]);
      }

    // publish gates (rows 0..7 only -> lanes qc<2)
    if (qc < 2) {
#pragma unroll
      for (int ut = 0; ut < 4; ++ut)
#pragma unroll
        for (int r = 0; r < 4; ++r)
          gbuf[g][qc * 4 + r][uhf * 64 + ut * 16 + jc] = acc[ut][r];
    }
    __syncthreads();  // barrier1: gates visible (and all A-reads complete)

    // cell phase: wave wv handles seq wv, lane -> units u0,u0+1
    v2f gI = *(const __shared__ v2f*)&gbuf[0][wv][u0];
    v2f gF = *(const __shared__ v2f*)&gbuf[1][wv][u0];
    v2f gG = *(const __shared__ v2f*)&gbuf[2][wv][u0];
    v2f gO = *(const __shared__ v2f*)&gbuf[3][wv][u0];
    float hA = cell_update(gI.x, gF.x, gG.x, gO.x, cA);
    float hB = cell_update(gI.y, gF.y, gG.y, gO.y, cB);

    // h -> hi/lo planes, packed dword writes (units u0,u0+1 adjacent)
    unsigned uA = __float_as_uint(hA), uB = __float_as_uint(hB);
    float hifA = __uint_as_float(uA & 0xffff0000u);
    float hifB = __uint_as_float(uB & 0xffff0000u);
    unsigned loA = __float_as_uint(hA - hifA) >> 16;
    unsigned loB = __float_as_uint(hB - hifB) >> 16;
    ((unsigned*)hph)[wv * 68 + lane] = (uA >> 16) | (uB & 0xffff0000u);
    ((unsigned*)hph)[1088 + wv * 68 + lane] = loA | (loB << 16);

    // pred partials + wave reduce (seq = wv)
    float p0 = hA * wpA0 + hB * wpA1;
    float p1 = hA * wpB0 + hB * wpB1;
#pragma unroll
    for (int off = 32; off > 0; off >>= 1) {
      p0 += __shfl_xor(p0, off, 64);
      p1 += __shfl_xor(p1, off, 64);
    }
    if (lane == 0) {
      out[(size_t)(s0 + wv) * (PRED_STEPS * 2) + t * 2 + 0] = p0 + bp0;
      out[(size_t)(s0 + wv) * (PRED_STEPS * 2) + t * 2 + 1] = p1 + bp1;
    }
    __syncthreads();  // barrier2: h planes visible for next A-read
  }
}

extern "C" void kernel_launch(void* const* d_in, const int* in_sizes, int n_in,
                              void* d_out, int out_size, void* d_ws, size_t ws_size,
                              hipStream_t stream) {
  (void)in_sizes; (void)n_in; (void)out_size; (void)ws_size;
  const float* xA    = (const float*)d_in[0];
  const float* xN    = (const float*)d_in[1];
  const int*   cnts  = (const int*)d_in[2];
  const float* Wih_a = (const float*)d_in[3];
  const float* Whh_a = (const float*)d_in[4];
  const float* bih_a = (const float*)d_in[5];
  const float* bhh_a = (const float*)d_in[6];
  const float* Wih_n = (const float*)d_in[7];
  const float* Whh_n = (const float*)d_in[8];
  const float* bih_n = (const float*)d_in[9];
  const float* bhh_n = (const float*)d_in[10];
  const float* Wih_d = (const float*)d_in[11];
  const float* Whh_d = (const float*)d_in[12];
  const float* bih_d = (const float*)d_in[13];
  const float* bhh_d = (const float*)d_in[14];
  const float* Wpos  = (const float*)d_in[15];
  const float* bpos  = (const float*)d_in[16];
  float* out = (float*)d_out;
  float* wsf = (float*)d_ws;

  prep_encpack<<<32, 256, 0, stream>>>(Whh_a, Whh_n,
                                       (uint4*)(wsf + OFF_PACKA),
                                       (uint4*)(wsf + OFF_PACKN));
  prep_decpack<<<64, 256, 0, stream>>>(Wih_d, Whh_d, bih_d, bhh_d,
                                       (uint4*)(wsf + OFF_WDP), wsf + OFF_WDB);
  enc_mfma_kernel<<<2176, 256, 0, stream>>>(
      xA, xN,
      (const v8s*)(wsf + OFF_PACKA), (const v8s*)(wsf + OFF_PACKN),
      Wih_a, bih_a, bhh_a, Wih_n, bih_n, bhh_n,
      wsf + OFF_AEMB, wsf + OFF_NENC);
  hmax_kernel<<<512, 256, 0, stream>>>(wsf + OFF_AEMB, wsf + OFF_NENC, cnts, wsf + OFF_H0);
  dec_mfma_kernel<<<256, 512, 0, stream>>>((const v8s*)(wsf + OFF_WDP),
                                           wsf + OFF_WDB, wsf + OFF_H0,
                                           Wpos, bpos, out);
}

// Round 7
// 349.048 us; speedup vs baseline: 1.4801x; 1.4801x over previous
//
#include <hip/hip_runtime.h>
#include <stdint.h>

// ---------------------------------------------------------------------------
// Social LSTM model, bf16x3 MFMA everywhere.
//   enc:  LSTM(2->64), T=50, 2176 blocks x 4 waves, 16 seqs/block.
//         Whh register-resident B-frags (hi/lo). Ping-pong h LDS planes
//         => 1 barrier/step. launch_bounds(256,3): (256,4) forced 64 VGPR
//         and spilled B-frags to scratch (R6: 109 MB HBM, enc 420 us).
//   pool: masked max over valid neighbours, concat -> h0 [2048,128]
//   dec:  LSTMCell(128->128), 30 steps. 256 blocks x 8 waves, 8 seqs/block.
//         B register-resident (128 VGPR/wave, loaded once). Gates cross
//         waves via padded LDS; cell phase wave w <-> seq w.
// Pointwise: shared-rcp sigmoid/tanh algebra (7 transcendentals/cell).
// ---------------------------------------------------------------------------

#define T_SEQ 50
#define PRED_STEPS 30
#define NMAX 16

typedef float v2f __attribute__((ext_vector_type(2)));
typedef float v4f __attribute__((ext_vector_type(4)));
typedef short v8s __attribute__((ext_vector_type(8)));

// ws layout (float offsets)
static constexpr size_t OFF_AEMB  = 0;          // 2048*64
static constexpr size_t OFF_NENC  = 131072;     // 32768*64
static constexpr size_t OFF_H0    = 2228224;    // 2048*128
static constexpr size_t OFF_PACKA = 2490368;    // 64 KB bf16 B-frags (agent)
static constexpr size_t OFF_PACKN = 2507520;    // 64 KB bf16 B-frags (neigh)
static constexpr size_t OFF_WDP   = 2524672;    // 256 KB dec bf16 B-frags
static constexpr size_t OFF_WDB   = 2590208;    // 512 fused dec bias

__device__ __forceinline__ float frcp(float x) { return __builtin_amdgcn_rcpf(x); }
__device__ __forceinline__ unsigned bf16rne(float f) {
  unsigned u = __float_as_uint(f);
  u += 0x7fff + ((u >> 16) & 1);
  return u >> 16;
}
__device__ __forceinline__ float bf16tof(unsigned h) { return __uint_as_float(h << 16); }
__device__ __forceinline__ v4f mfma16(v8s a, v8s b, v4f c) {
  return __builtin_amdgcn_mfma_f32_16x16x32_bf16(a, b, c, 0, 0, 0);
}

// Shared-rcp LSTM cell update (7 transcendentals).
__device__ __forceinline__ float cell_update(float iv, float fv, float gv,
                                             float ov, float& cref) {
  float ef = __expf(-fv);
  float ei = __expf(-iv);
  float eg = __expf(-2.f * gv);
  float t1 = (1.f + ei) * (1.f + eg);
  float rD = frcp((1.f + ef) * t1);
  float sf = t1 * rD;
  float u  = (1.f - eg) * ((1.f + ef) * rD);
  float cn = fmaf(sf, cref, u);
  cref = cn;
  float eo = __expf(-ov);
  float ec = __expf(fminf(-2.f * cn, 41.5f));
  return (1.f - ec) * frcp((1.f + eo) * (1.f + ec));
}

// ---------------------------------------------------------------------------
// Prep: encoder Whh as MFMA B-fragments, bf16 hi/lo split (RNE).
// ---------------------------------------------------------------------------
__global__ void prep_encpack(const float* __restrict__ Whh_a, const float* __restrict__ Whh_n,
                             uint4* __restrict__ packA, uint4* __restrict__ packN) {
  const int which = blockIdx.x >> 4;
  const int idx = (blockIdx.x & 15) * 256 + threadIdx.x;  // 0..4095
  const float* Whh = which ? Whh_n : Whh_a;
  uint4* dst = which ? packN : packA;
  const int lane = idx & 63, c = idx >> 6;
  const int p = c & 1, kh = (c >> 1) & 1, g = (c >> 2) & 3, w = (c >> 4) & 3;
  const int row = g * 64 + 16 * w + (lane & 15);
  const int kb = kh * 32 + (lane >> 4) * 8;
  unsigned us[8];
#pragma unroll
  for (int e = 0; e < 8; ++e) {
    float W = Whh[row * 64 + kb + e];
    unsigned hi = bf16rne(W);
    us[e] = p ? bf16rne(W - bf16tof(hi)) : hi;
  }
  uint4 o;
  o.x = us[0] | (us[1] << 16);
  o.y = us[2] | (us[3] << 16);
  o.z = us[4] | (us[5] << 16);
  o.w = us[6] | (us[7] << 16);
  dst[c * 64 + lane] = o;
}

// ---------------------------------------------------------------------------
// Prep: decoder fused W = Wih_d + Whh_d as B-frags (bf16 hi/lo).
// chunk c = (g<<6)|(uhf<<5)|(ut<<3)|(kh<<1)|p ; 256 chunks x 1 KB.
// ---------------------------------------------------------------------------
__global__ void prep_decpack(const float* __restrict__ Wih, const float* __restrict__ Whh,
                             const float* __restrict__ bih, const float* __restrict__ bhh,
                             uint4* __restrict__ dst, float* __restrict__ bd) {
  const int idx = blockIdx.x * 256 + threadIdx.x;  // 0..16383
  const int lane = idx & 63, c = idx >> 6;
  const int p = c & 1, kh = (c >> 1) & 3, ut = (c >> 3) & 3, uhf = (c >> 5) & 1, g = (c >> 6) & 3;
  const int j = uhf * 64 + ut * 16 + (lane & 15);
  const int row = g * 128 + j;
  const int kb = kh * 32 + (lane >> 4) * 8;
  unsigned us[8];
#pragma unroll
  for (int e = 0; e < 8; ++e) {
    float W = Wih[row * 128 + kb + e] + Whh[row * 128 + kb + e];
    unsigned hi = bf16rne(W);
    us[e] = p ? bf16rne(W - bf16tof(hi)) : hi;
  }
  uint4 o;
  o.x = us[0] | (us[1] << 16);
  o.y = us[2] | (us[3] << 16);
  o.z = us[4] | (us[5] << 16);
  o.w = us[6] | (us[7] << 16);
  dst[c * 64 + lane] = o;
  if (blockIdx.x < 2) {
    int i = blockIdx.x * 256 + threadIdx.x;  // 0..511
    bd[i] = bih[i] + bhh[i];
  }
}

// ---------------------------------------------------------------------------
// Encoder. Blocks [0,2048) neighbour, [2048,2176) agent; 256 thr = 4 waves.
// Ping-pong h planes: buf b at halfword base b*2304; hi [+0,+1152),
// lo [+1152,+2304); row stride 72 halfwords (16B-aligned b128 reads).
// One barrier per timestep.
// ---------------------------------------------------------------------------
__global__ __launch_bounds__(256, 3) void enc_mfma_kernel(
    const float* __restrict__ xA, const float* __restrict__ xN,
    const v8s* __restrict__ packA, const v8s* __restrict__ packN,
    const float* __restrict__ Wih_a, const float* __restrict__ bih_a, const float* __restrict__ bhh_a,
    const float* __restrict__ Wih_n, const float* __restrict__ bih_n, const float* __restrict__ bhh_n,
    float* __restrict__ outA, float* __restrict__ outN) {
  __shared__ unsigned short hph[4608];  // 2 ping-pong buffers
  __shared__ float xst[1600];
  const int tid = threadIdx.x, lane = tid & 63, wv = tid >> 6;
  const int nb = blockIdx.x;
  const bool isA = nb >= 2048;
  const float* xsrc = isA ? xA : xN;
  const v8s* pk = isA ? packA : packN;
  const float* Wih = isA ? Wih_a : Wih_n;
  const float* bih = isA ? bih_a : bih_n;
  const float* bhh = isA ? bhh_a : bhh_n;
  float* outp = isA ? outA : outN;
  const int s0 = (isA ? nb - 2048 : nb) * 16;

  // register-resident B fragments: [gate][khalf][hi/lo]
  v8s B[4][2][2];
#pragma unroll
  for (int g = 0; g < 4; ++g)
#pragma unroll
    for (int kh = 0; kh < 2; ++kh)
#pragma unroll
      for (int p = 0; p < 2; ++p)
        B[g][kh][p] = pk[((((wv * 4 + g) * 2 + kh) * 2 + p) << 6) + lane];

  const int jc = lane & 15, qc = lane >> 4;  // C roles: unit col, seq quad
  float wi0[4], wi1[4], bs[4];
#pragma unroll
  for (int g = 0; g < 4; ++g) {
    int n = g * 64 + 16 * wv + jc;
    wi0[g] = Wih[n * 2 + 0];
    wi1[g] = Wih[n * 2 + 1];
    bs[g] = bih[n] + bhh[n];
  }

  // stage x (1600 floats) + zero buf0 (1152 dwords = 2304 halfwords)
  {
    const float4* xb = (const float4*)(xsrc + (size_t)s0 * 100);
    for (int i = tid; i < 400; i += 256) ((float4*)xst)[i] = xb[i];
    for (int i = tid; i < 1152; i += 256) ((unsigned*)hph)[i] = 0;
  }
  __syncthreads();

  const int ms = lane & 15, ks = lane >> 4;  // A roles: seq row, k-quad
  float cst[4] = {0.f, 0.f, 0.f, 0.f};
  float h[4];

  for (int t = 0; t < T_SEQ; ++t) {
    const int rb = (t & 1) * 2304;          // read buffer base
    const int wb = 2304 - rb;               // write buffer base
    v8s Ahi[2], Alo[2];
#pragma unroll
    for (int kh = 0; kh < 2; ++kh) {
      Ahi[kh] = *(const __shared__ v8s*)&hph[rb + ms * 72 + kh * 32 + ks * 8];
      Alo[kh] = *(const __shared__ v8s*)&hph[rb + 1152 + ms * 72 + kh * 32 + ks * 8];
    }

    // acc init: exact fp32 input projection + bias
    v4f a4[4];
#pragma unroll
    for (int r = 0; r < 4; ++r) {
      v2f xv = *(const __shared__ v2f*)&xst[(qc * 4 + r) * 100 + 2 * t];
#pragma unroll
      for (int g = 0; g < 4; ++g)
        a4[g][r] = fmaf(wi1[g], xv.y, fmaf(wi0[g], xv.x, bs[g]));
    }

    // h @ Whh^T via bf16x3 MFMA
#pragma unroll
    for (int g = 0; g < 4; ++g)
#pragma unroll
      for (int kh = 0; kh < 2; ++kh) {
        a4[g] = mfma16(Ahi[kh], B[g][kh][0], a4[g]);
        a4[g] = mfma16(Ahi[kh], B[g][kh][1], a4[g]);
        a4[g] = mfma16(Alo[kh], B[g][kh][0], a4[g]);
      }

    // pointwise + truncation-split b16 stores into the OTHER buffer
#pragma unroll
    for (int r = 0; r < 4; ++r) {
      h[r] = cell_update(a4[0][r], a4[1][r], a4[2][r], a4[3][r], cst[r]);
      unsigned uu = __float_as_uint(h[r]);
      float hif = __uint_as_float(uu & 0xffff0000u);
      float lof = h[r] - hif;
      int ha = wb + (qc * 4 + r) * 72 + 16 * wv + jc;
      hph[ha] = (unsigned short)(uu >> 16);
      hph[1152 + ha] = (unsigned short)(__float_as_uint(lof) >> 16);
    }
    __syncthreads();  // single barrier: writes visible for next-step reads
  }

#pragma unroll
  for (int r = 0; r < 4; ++r)
    outp[(size_t)(s0 + qc * 4 + r) * 64 + 16 * wv + jc] = h[r];
}

// Masked neighbour max-pool + concat -> h0 [B,128]
__global__ void hmax_kernel(const float* __restrict__ aemb, const float* __restrict__ nenc,
                            const int* __restrict__ cnts, float* __restrict__ h0) {
  const int idx = blockIdx.x * 256 + threadIdx.x;  // 2048*64
  const int b = idx >> 6, j = idx & 63;
  h0[(size_t)b * 128 + j] = aemb[(size_t)b * 64 + j];
  const int cnt = cnts[b];
  float m = -1e30f;
  for (int n = 0; n < cnt; ++n) m = fmaxf(m, nenc[((size_t)(b * NMAX + n)) * 64 + j]);
  h0[(size_t)b * 128 + 64 + j] = (cnt > 0) ? m : 0.f;
}

// ---------------------------------------------------------------------------
// Decoder MFMA v2. 256 blocks x 512 thr (8 waves), 8 seqs/block.
// Wave wv: gate g = wv&3, unit-half uhf = wv>>2 -> 4 col-tiles of 16 units.
// B register-resident (32 v8s = 128 VGPR), loaded ONCE before the t-loop.
// ---------------------------------------------------------------------------
__global__ __launch_bounds__(512, 2) void dec_mfma_kernel(
    const v8s* __restrict__ pkd, const float* __restrict__ bd,
    const float* __restrict__ h0, const float* __restrict__ Wpos,
    const float* __restrict__ bpos, float* __restrict__ out) {
  __shared__ unsigned short hph[4352];
  __shared__ float gbuf[4][8][132];
  const int tid = threadIdx.x, lane = tid & 63, wv = tid >> 6;
  const int jc = lane & 15, qc = lane >> 4;
  const int g = wv & 3, uhf = wv >> 2;
  const int s0 = blockIdx.x * 8;

  // register-resident B fragments: [utile][kh][hi/lo]
  v8s B[4][4][2];
#pragma unroll
  for (int ut = 0; ut < 4; ++ut)
#pragma unroll
    for (int kh = 0; kh < 4; ++kh)
#pragma unroll
      for (int p = 0; p < 2; ++p) {
        int c = (g << 6) | (uhf << 5) | (ut << 3) | (kh << 1) | p;
        B[ut][kh][p] = pkd[(c << 6) + lane];
      }
  float bs[4];
#pragma unroll
  for (int ut = 0; ut < 4; ++ut)
    bs[ut] = bd[g * 128 + uhf * 64 + ut * 16 + jc];

  // per-thread cell/pred constants: seq = wv, units u0=2*lane, u0+1
  const int u0 = 2 * lane;
  const float wpA0 = Wpos[u0], wpA1 = Wpos[u0 + 1];
  const float wpB0 = Wpos[128 + u0], wpB1 = Wpos[128 + u0 + 1];
  const float bp0 = bpos[0], bp1 = bpos[1];

  // stage h0 (rows 0..7) + zero rows 8..15
  for (int i = tid; i < 2048; i += 512) {
    int row = i >> 7, unit = i & 127;
    unsigned hiw = 0, low = 0;
    if (row < 8) {
      float v = h0[(size_t)(s0 + row) * 128 + unit];
      unsigned u = __float_as_uint(v);
      float hif = __uint_as_float(u & 0xffff0000u);
      float lof = v - hif;
      hiw = u >> 16;
      low = __float_as_uint(lof) >> 16;
    }
    hph[row * 136 + unit] = (unsigned short)hiw;
    hph[2176 + row * 136 + unit] = (unsigned short)low;
  }
  float cA = 0.f, cB = 0.f;
  __syncthreads();

  for (int t = 0; t < PRED_STEPS; ++t) {
    // A fragments (rows = seqs, rows 8-15 zero)
    v8s Ahi[4], Alo[4];
#pragma unroll
    for (int kh = 0; kh < 4; ++kh) {
      Ahi[kh] = *(const __shared__ v8s*)&hph[jc * 136 + kh * 32 + qc * 8];
      Alo[kh] = *(const __shared__ v8s*)&hph[2176 + jc * 136 + kh * 32 + qc * 8];
    }

    // gates for this wave's 4 col-tiles
    v4f acc[4];
#pragma unroll
    for (int ut = 0; ut < 4; ++ut)
      acc[ut] = (v4f){bs[ut], bs[ut], bs[ut], bs[ut]};
#pragma unroll
    for (int ut = 0; ut < 4; ++ut)
#pragma unroll
      for (int kh = 0; kh < 4; ++kh) {
        acc[ut] = mfma16(Ahi[kh], B[ut][kh][0], acc[ut]);
        acc[ut] = mfma16(Ahi[kh], B[ut][kh][1], acc[ut]);
        acc[ut] = mfma16(Alo[kh], B[ut][kh][0], acc[ut]);
      }

    // publish gates (rows 0..7 only -> lanes qc<2)
    if (qc < 2) {
#pragma unroll
      for (int ut = 0; ut < 4; ++ut)
#pragma unroll
        for (int r = 0; r < 4; ++r)
          gbuf[g][qc * 4 + r][uhf * 64 + ut * 16 + jc] = acc[ut][r];
    }
    __syncthreads();  // barrier1: gates visible (and all A-reads complete)

    // cell phase: wave wv handles seq wv, lane -> units u0,u0+1
    v2f gI = *(const __shared__ v2f*)&gbuf[0][wv][u0];
    v2f gF = *(const __shared__ v2f*)&gbuf[1][wv][u0];
    v2f gG = *(const __shared__ v2f*)&gbuf[2][wv][u0];
    v2f gO = *(const __shared__ v2f*)&gbuf[3][wv][u0];
    float hA = cell_update(gI.x, gF.x, gG.x, gO.x, cA);
    float hB = cell_update(gI.y, gF.y, gG.y, gO.y, cB);

    // h -> hi/lo planes, packed dword writes (units u0,u0+1 adjacent)
    unsigned uA = __float_as_uint(hA), uB = __float_as_uint(hB);
    float hifA = __uint_as_float(uA & 0xffff0000u);
    float hifB = __uint_as_float(uB & 0xffff0000u);
    unsigned loA = __float_as_uint(hA - hifA) >> 16;
    unsigned loB = __float_as_uint(hB - hifB) >> 16;
    ((unsigned*)hph)[wv * 68 + lane] = (uA >> 16) | (uB & 0xffff0000u);
    ((unsigned*)hph)[1088 + wv * 68 + lane] = loA | (loB << 16);

    // pred partials + wave reduce (seq = wv)
    float p0 = hA * wpA0 + hB * wpA1;
    float p1 = hA * wpB0 + hB * wpB1;
#pragma unroll
    for (int off = 32; off > 0; off >>= 1) {
      p0 += __shfl_xor(p0, off, 64);
      p1 += __shfl_xor(p1, off, 64);
    }
    if (lane == 0) {
      out[(size_t)(s0 + wv) * (PRED_STEPS * 2) + t * 2 + 0] = p0 + bp0;
      out[(size_t)(s0 + wv) * (PRED_STEPS * 2) + t * 2 + 1] = p1 + bp1;
    }
    __syncthreads();  // barrier2: h planes visible for next A-read
  }
}

extern "C" void kernel_launch(void* const* d_in, const int* in_sizes, int n_in,
                              void* d_out, int out_size, void* d_ws, size_t ws_size,
                              hipStream_t stream) {
  (void)in_sizes; (void)n_in; (void)out_size; (void)ws_size;
  const float* xA    = (const float*)d_in[0];
  const float* xN    = (const float*)d_in[1];
  const int*   cnts  = (const int*)d_in[2];
  const float* Wih_a = (const float*)d_in[3];
  const float* Whh_a = (const float*)d_in[4];
  const float* bih_a = (const float*)d_in[5];
  const float* bhh_a = (const float*)d_in[6];
  const float* Wih_n = (const float*)d_in[7];
  const float* Whh_n = (const float*)d_in[8];
  const float* bih_n = (const float*)d_in[9];
  const float* bhh_n = (const float*)d_in[10];
  const float* Wih_d = (const float*)d_in[11];
  const float* Whh_d = (const float*)d_in[12];
  const float* bih_d = (const float*)d_in[13];
  const float* bhh_d = (const float*)d_in[14];
  const float* Wpos  = (const float*)d_in[15];
  const float* bpos  = (const float*)d_in[16];
  float* out = (float*)d_out;
  float* wsf = (float*)d_ws;

  prep_encpack<<<32, 256, 0, stream>>>(Whh_a, Whh_n,
                                       (uint4*)(wsf + OFF_PACKA),
                                       (uint4*)(wsf + OFF_PACKN));
  prep_decpack<<<64, 256, 0, stream>>>(Wih_d, Whh_d, bih_d, bhh_d,
                                       (uint4*)(wsf + OFF_WDP), wsf + OFF_WDB);
  enc_mfma_kernel<<<2176, 256, 0, stream>>>(
      xA, xN,
      (const v8s*)(wsf + OFF_PACKA), (const v8s*)(wsf + OFF_PACKN),
      Wih_a, bih_a, bhh_a, Wih_n, bih_n, bhh_n,
      wsf + OFF_AEMB, wsf + OFF_NENC);
  hmax_kernel<<<512, 256, 0, stream>>>(wsf + OFF_AEMB, wsf + OFF_NENC, cnts, wsf + OFF_H0);
  dec_mfma_kernel<<<256, 512, 0, stream>>>((const v8s*)(wsf + OFF_WDP),
                                           wsf + OFF_WDB, wsf + OFF_H0,
                                           Wpos, bpos, out);
}

// Round 8
// 344.432 us; speedup vs baseline: 1.4999x; 1.0134x over previous
//
#include <hip/hip_runtime.h>
#include <stdint.h>

// ---------------------------------------------------------------------------
// Social LSTM model, bf16x3 MFMA everywhere.
//   enc:  LSTM(2->64), T=50, 2176 blocks x 4 waves, 16 seqs/block.
//         Whh register-resident B-frags (hi/lo). Ping-pong h LDS planes,
//         t-loop unrolled x2 so all LDS addresses are base+imm (R7 showed
//         ~150 cyc/wave-step of address recompute fat).
//   pool: fused into dec staging (masked max over nenc).
//   dec:  LSTMCell(128->128), 30 steps. 256 blocks x 8 waves, 8 seqs/block.
//         B register-resident, loaded once; gates cross waves via LDS.
// Pointwise: shared-rcp sigmoid/tanh algebra; g-gate weights pre-scaled by
// 2 in prep so eg = expf(-g_hat) (one fewer mul per cell).
// launch_bounds notes: enc (256,3) -- (256,4) forces 64 VGPR + scratch
// spill (R6: 109 MB HBM, 420 us). dec (512,2).
// ---------------------------------------------------------------------------

#define T_SEQ 50
#define PRED_STEPS 30
#define NMAX 16

typedef float v2f __attribute__((ext_vector_type(2)));
typedef float v4f __attribute__((ext_vector_type(4)));
typedef short v8s __attribute__((ext_vector_type(8)));

// ws layout (float offsets)
static constexpr size_t OFF_AEMB  = 0;          // 2048*64
static constexpr size_t OFF_NENC  = 131072;     // 32768*64
static constexpr size_t OFF_PACKA = 2490368;    // 64 KB bf16 B-frags (agent)
static constexpr size_t OFF_PACKN = 2507520;    // 64 KB bf16 B-frags (neigh)
static constexpr size_t OFF_WDP   = 2524672;    // 256 KB dec bf16 B-frags
static constexpr size_t OFF_WDB   = 2590208;    // 512 fused dec bias

__device__ __forceinline__ float frcp(float x) { return __builtin_amdgcn_rcpf(x); }
__device__ __forceinline__ unsigned bf16rne(float f) {
  unsigned u = __float_as_uint(f);
  u += 0x7fff + ((u >> 16) & 1);
  return u >> 16;
}
__device__ __forceinline__ float bf16tof(unsigned h) { return __uint_as_float(h << 16); }
__device__ __forceinline__ v4f mfma16(v8s a, v8s b, v4f c) {
  return __builtin_amdgcn_mfma_f32_16x16x32_bf16(a, b, c, 0, 0, 0);
}

// Shared-rcp LSTM cell update. gv is PRE-SCALED by 2 (prep folds it into
// the g-gate weights): eg = exp(-2*g_true) = expf(-gv).
__device__ __forceinline__ float cell_update(float iv, float fv, float gv,
                                             float ov, float& cref) {
  float ef = __expf(-fv);
  float ei = __expf(-iv);
  float eg = __expf(-gv);
  float t1 = (1.f + ei) * (1.f + eg);
  float rD = frcp((1.f + ef) * t1);
  float sf = t1 * rD;
  float u  = (1.f - eg) * ((1.f + ef) * rD);
  float cn = fmaf(sf, cref, u);
  cref = cn;
  float eo = __expf(-ov);
  float ec = __expf(fminf(-2.f * cn, 41.5f));
  return (1.f - ec) * frcp((1.f + eo) * (1.f + ec));
}

// ---------------------------------------------------------------------------
// Merged prep. Blocks 0..31: encoder packs (which = b>>4).
// Blocks 32..95: decoder pack (+ bias on first two).
// g-gate (g==2) weights and bias scaled by 2.
// ---------------------------------------------------------------------------
__global__ void prep_kernel(const float* __restrict__ Whh_a, const float* __restrict__ Whh_n,
                            const float* __restrict__ Wih_d, const float* __restrict__ Whh_d,
                            const float* __restrict__ bih_d, const float* __restrict__ bhh_d,
                            uint4* __restrict__ packA, uint4* __restrict__ packN,
                            uint4* __restrict__ packD, float* __restrict__ bd) {
  if (blockIdx.x < 32) {
    const int which = blockIdx.x >> 4;
    const int idx = (blockIdx.x & 15) * 256 + threadIdx.x;  // 0..4095
    const float* Whh = which ? Whh_n : Whh_a;
    uint4* dst = which ? packN : packA;
    const int lane = idx & 63, c = idx >> 6;
    const int p = c & 1, kh = (c >> 1) & 1, g = (c >> 2) & 3, w = (c >> 4) & 3;
    const float gs = (g == 2) ? 2.f : 1.f;
    const int row = g * 64 + 16 * w + (lane & 15);
    const int kb = kh * 32 + (lane >> 4) * 8;
    unsigned us[8];
#pragma unroll
    for (int e = 0; e < 8; ++e) {
      float W = Whh[row * 64 + kb + e] * gs;
      unsigned hi = bf16rne(W);
      us[e] = p ? bf16rne(W - bf16tof(hi)) : hi;
    }
    uint4 o;
    o.x = us[0] | (us[1] << 16);
    o.y = us[2] | (us[3] << 16);
    o.z = us[4] | (us[5] << 16);
    o.w = us[6] | (us[7] << 16);
    dst[c * 64 + lane] = o;
  } else {
    const int idx = (blockIdx.x - 32) * 256 + threadIdx.x;  // 0..16383
    const int lane = idx & 63, c = idx >> 6;
    const int p = c & 1, kh = (c >> 1) & 3, ut = (c >> 3) & 3, uhf = (c >> 5) & 1, g = (c >> 6) & 3;
    const float gs = (g == 2) ? 2.f : 1.f;
    const int j = uhf * 64 + ut * 16 + (lane & 15);
    const int row = g * 128 + j;
    const int kb = kh * 32 + (lane >> 4) * 8;
    unsigned us[8];
#pragma unroll
    for (int e = 0; e < 8; ++e) {
      float W = (Wih_d[row * 128 + kb + e] + Whh_d[row * 128 + kb + e]) * gs;
      unsigned hi = bf16rne(W);
      us[e] = p ? bf16rne(W - bf16tof(hi)) : hi;
    }
    uint4 o;
    o.x = us[0] | (us[1] << 16);
    o.y = us[2] | (us[3] << 16);
    o.z = us[4] | (us[5] << 16);
    o.w = us[6] | (us[7] << 16);
    packD[c * 64 + lane] = o;
    if (blockIdx.x < 34) {
      int i = (blockIdx.x - 32) * 256 + threadIdx.x;  // 0..511
      float s = ((i >> 7) == 2) ? 2.f : 1.f;
      bd[i] = (bih_d[i] + bhh_d[i]) * s;
    }
  }
}

// ---------------------------------------------------------------------------
// Encoder. Blocks [0,2048) neighbour, [2048,2176) agent; 256 thr = 4 waves.
// Ping-pong h planes: buf b at halfword base b*2304; hi [+0,+1152),
// lo [+1152,+2304); row stride 72 halfwords. t-loop unrolled x2 so the
// buffer bases are literals (LDS addresses = base reg + imm offset).
// ---------------------------------------------------------------------------
__global__ __launch_bounds__(256, 3) void enc_mfma_kernel(
    const float* __restrict__ xA, const float* __restrict__ xN,
    const v8s* __restrict__ packA, const v8s* __restrict__ packN,
    const float* __restrict__ Wih_a, const float* __restrict__ bih_a, const float* __restrict__ bhh_a,
    const float* __restrict__ Wih_n, const float* __restrict__ bih_n, const float* __restrict__ bhh_n,
    float* __restrict__ outA, float* __restrict__ outN) {
  __shared__ unsigned short hph[4608];  // 2 ping-pong buffers
  __shared__ float xst[1600];
  const int tid = threadIdx.x, lane = tid & 63, wv = tid >> 6;
  const int nb = blockIdx.x;
  const bool isA = nb >= 2048;
  const float* xsrc = isA ? xA : xN;
  const v8s* pk = isA ? packA : packN;
  const float* Wih = isA ? Wih_a : Wih_n;
  const float* bih = isA ? bih_a : bih_n;
  const float* bhh = isA ? bhh_a : bhh_n;
  float* outp = isA ? outA : outN;
  const int s0 = (isA ? nb - 2048 : nb) * 16;

  // register-resident B fragments: [gate][khalf][hi/lo]
  v8s B[4][2][2];
#pragma unroll
  for (int g = 0; g < 4; ++g)
#pragma unroll
    for (int kh = 0; kh < 2; ++kh)
#pragma unroll
      for (int p = 0; p < 2; ++p)
        B[g][kh][p] = pk[((((wv * 4 + g) * 2 + kh) * 2 + p) << 6) + lane];

  const int jc = lane & 15, qc = lane >> 4;  // C roles: unit col, seq quad
  float wi0[4], wi1[4], bs[4];
#pragma unroll
  for (int g = 0; g < 4; ++g) {
    const float gs = (g == 2) ? 2.f : 1.f;
    int n = g * 64 + 16 * wv + jc;
    wi0[g] = Wih[n * 2 + 0] * gs;
    wi1[g] = Wih[n * 2 + 1] * gs;
    bs[g] = (bih[n] + bhh[n]) * gs;
  }

  // stage x (1600 floats) + zero buf0 (1152 dwords)
  {
    const float4* xb = (const float4*)(xsrc + (size_t)s0 * 100);
    for (int i = tid; i < 400; i += 256) ((float4*)xst)[i] = xb[i];
    for (int i = tid; i < 1152; i += 256) ((unsigned*)hph)[i] = 0;
  }
  __syncthreads();

  const int ms = lane & 15, ks = lane >> 4;  // A roles: seq row, k-quad
  float cst[4] = {0.f, 0.f, 0.f, 0.f};
  float h[4];

  auto enc_step = [&](int t, int rb, int wb) {
    v8s Ahi[2], Alo[2];
#pragma unroll
    for (int kh = 0; kh < 2; ++kh) {
      Ahi[kh] = *(const __shared__ v8s*)&hph[rb + ms * 72 + kh * 32 + ks * 8];
      Alo[kh] = *(const __shared__ v8s*)&hph[rb + 1152 + ms * 72 + kh * 32 + ks * 8];
    }

    // acc init: exact fp32 input projection + bias
    v4f a4[4];
#pragma unroll
    for (int r = 0; r < 4; ++r) {
      v2f xv = *(const __shared__ v2f*)&xst[(qc * 4 + r) * 100 + 2 * t];
#pragma unroll
      for (int g = 0; g < 4; ++g)
        a4[g][r] = fmaf(wi1[g], xv.y, fmaf(wi0[g], xv.x, bs[g]));
    }

    // h @ Whh^T via bf16x3 MFMA
#pragma unroll
    for (int g = 0; g < 4; ++g)
#pragma unroll
      for (int kh = 0; kh < 2; ++kh) {
        a4[g] = mfma16(Ahi[kh], B[g][kh][0], a4[g]);
        a4[g] = mfma16(Ahi[kh], B[g][kh][1], a4[g]);
        a4[g] = mfma16(Alo[kh], B[g][kh][0], a4[g]);
      }

    // pointwise + truncation-split b16 stores into the OTHER buffer
#pragma unroll
    for (int r = 0; r < 4; ++r) {
      h[r] = cell_update(a4[0][r], a4[1][r], a4[2][r], a4[3][r], cst[r]);
      unsigned uu = __float_as_uint(h[r]);
      float hif = __uint_as_float(uu & 0xffff0000u);
      float lof = h[r] - hif;
      int ha = wb + (qc * 4 + r) * 72 + 16 * wv + jc;
      hph[ha] = (unsigned short)(uu >> 16);
      hph[1152 + ha] = (unsigned short)(__float_as_uint(lof) >> 16);
    }
    __syncthreads();
  };

  for (int t2 = 0; t2 < T_SEQ; t2 += 2) {
    enc_step(t2 + 0, 0, 2304);      // literal bases -> imm LDS offsets
    enc_step(t2 + 1, 2304, 0);
  }

#pragma unroll
  for (int r = 0; r < 4; ++r)
    outp[(size_t)(s0 + qc * 4 + r) * 64 + 16 * wv + jc] = h[r];
}

// ---------------------------------------------------------------------------
// Decoder MFMA v3. 256 blocks x 512 thr (8 waves), 8 seqs/block.
// Staging FUSES the masked neighbour max-pool (reads aemb/nenc/cnts).
// Wave wv: gate g = wv&3, unit-half uhf = wv>>2 -> 4 col-tiles of 16 units.
// B register-resident (32 v8s = 128 VGPR), loaded ONCE.
// ---------------------------------------------------------------------------
__global__ __launch_bounds__(512, 2) void dec_mfma_kernel(
    const v8s* __restrict__ pkd, const float* __restrict__ bd,
    const float* __restrict__ aemb, const float* __restrict__ nenc,
    const int* __restrict__ cnts, const float* __restrict__ Wpos,
    const float* __restrict__ bpos, float* __restrict__ out) {
  __shared__ unsigned short hph[4352];
  __shared__ float gbuf[4][8][132];
  const int tid = threadIdx.x, lane = tid & 63, wv = tid >> 6;
  const int jc = lane & 15, qc = lane >> 4;
  const int g = wv & 3, uhf = wv >> 2;
  const int s0 = blockIdx.x * 8;

  // register-resident B fragments: [utile][kh][hi/lo]
  v8s B[4][4][2];
#pragma unroll
  for (int ut = 0; ut < 4; ++ut)
#pragma unroll
    for (int kh = 0; kh < 4; ++kh)
#pragma unroll
      for (int p = 0; p < 2; ++p) {
        int c = (g << 6) | (uhf << 5) | (ut << 3) | (kh << 1) | p;
        B[ut][kh][p] = pkd[(c << 6) + lane];
      }
  float bs[4];
#pragma unroll
  for (int ut = 0; ut < 4; ++ut)
    bs[ut] = bd[g * 128 + uhf * 64 + ut * 16 + jc];

  const int u0 = 2 * lane;
  const float wpA0 = Wpos[u0], wpA1 = Wpos[u0 + 1];
  const float wpB0 = Wpos[128 + u0], wpB1 = Wpos[128 + u0 + 1];
  const float bp0 = bpos[0], bp1 = bpos[1];

  // stage h0 rows 0..7 (fused hmax) + zero rows 8..15.
  // i=tid: each wave sees a uniform (row, agent-vs-neigh) split.
  for (int i = tid; i < 2048; i += 512) {
    int row = i >> 7, unit = i & 127;
    unsigned hiw = 0, low = 0;
    if (row < 8) {
      float v;
      if (unit < 64) {
        v = aemb[(size_t)(s0 + row) * 64 + unit];
      } else {
        int cnt = cnts[s0 + row];
        float m = -1e30f;
        for (int n = 0; n < cnt; ++n)
          m = fmaxf(m, nenc[((size_t)((s0 + row) * NMAX + n)) * 64 + (unit - 64)]);
        v = (cnt > 0) ? m : 0.f;
      }
      unsigned u = __float_as_uint(v);
      float hif = __uint_as_float(u & 0xffff0000u);
      float lof = v - hif;
      hiw = u >> 16;
      low = __float_as_uint(lof) >> 16;
    }
    hph[row * 136 + unit] = (unsigned short)hiw;
    hph[2176 + row * 136 + unit] = (unsigned short)low;
  }
  float cA = 0.f, cB = 0.f;
  __syncthreads();

  for (int t = 0; t < PRED_STEPS; ++t) {
    v8s Ahi[4], Alo[4];
#pragma unroll
    for (int kh = 0; kh < 4; ++kh) {
      Ahi[kh] = *(const __shared__ v8s*)&hph[jc * 136 + kh * 32 + qc * 8];
      Alo[kh] = *(const __shared__ v8s*)&hph[2176 + jc * 136 + kh * 32 + qc * 8];
    }

    v4f acc[4];
#pragma unroll
    for (int ut = 0; ut < 4; ++ut)
      acc[ut] = (v4f){bs[ut], bs[ut], bs[ut], bs[ut]};
#pragma unroll
    for (int ut = 0; ut < 4; ++ut)
#pragma unroll
      for (int kh = 0; kh < 4; ++kh) {
        acc[ut] = mfma16(Ahi[kh], B[ut][kh][0], acc[ut]);
        acc[ut] = mfma16(Ahi[kh], B[ut][kh][1], acc[ut]);
        acc[ut] = mfma16(Alo[kh], B[ut][kh][0], acc[ut]);
      }

    // publish gates (rows 0..7 only -> lanes qc<2)
    if (qc < 2) {
#pragma unroll
      for (int ut = 0; ut < 4; ++ut)
#pragma unroll
        for (int r = 0; r < 4; ++r)
          gbuf[g][qc * 4 + r][uhf * 64 + ut * 16 + jc] = acc[ut][r];
    }
    __syncthreads();  // barrier1: gates visible (A-reads complete)

    // cell phase: wave wv <-> seq wv, lane -> units u0,u0+1
    v2f gI = *(const __shared__ v2f*)&gbuf[0][wv][u0];
    v2f gF = *(const __shared__ v2f*)&gbuf[1][wv][u0];
    v2f gG = *(const __shared__ v2f*)&gbuf[2][wv][u0];
    v2f gO = *(const __shared__ v2f*)&gbuf[3][wv][u0];
    float hA = cell_update(gI.x, gF.x, gG.x, gO.x, cA);
    float hB = cell_update(gI.y, gF.y, gG.y, gO.y, cB);

    unsigned uA = __float_as_uint(hA), uB = __float_as_uint(hB);
    float hifA = __uint_as_float(uA & 0xffff0000u);
    float hifB = __uint_as_float(uB & 0xffff0000u);
    unsigned loA = __float_as_uint(hA - hifA) >> 16;
    unsigned loB = __float_as_uint(hB - hifB) >> 16;
    ((unsigned*)hph)[wv * 68 + lane] = (uA >> 16) | (uB & 0xffff0000u);
    ((unsigned*)hph)[1088 + wv * 68 + lane] = loA | (loB << 16);

    float p0 = hA * wpA0 + hB * wpA1;
    float p1 = hA * wpB0 + hB * wpB1;
#pragma unroll
    for (int off = 32; off > 0; off >>= 1) {
      p0 += __shfl_xor(p0, off, 64);
      p1 += __shfl_xor(p1, off, 64);
    }
    if (lane == 0) {
      out[(size_t)(s0 + wv) * (PRED_STEPS * 2) + t * 2 + 0] = p0 + bp0;
      out[(size_t)(s0 + wv) * (PRED_STEPS * 2) + t * 2 + 1] = p1 + bp1;
    }
    __syncthreads();  // barrier2: h planes visible for next A-read
  }
}

extern "C" void kernel_launch(void* const* d_in, const int* in_sizes, int n_in,
                              void* d_out, int out_size, void* d_ws, size_t ws_size,
                              hipStream_t stream) {
  (void)in_sizes; (void)n_in; (void)out_size; (void)ws_size;
  const float* xA    = (const float*)d_in[0];
  const float* xN    = (const float*)d_in[1];
  const int*   cnts  = (const int*)d_in[2];
  const float* Wih_a = (const float*)d_in[3];
  const float* Whh_a = (const float*)d_in[4];
  const float* bih_a = (const float*)d_in[5];
  const float* bhh_a = (const float*)d_in[6];
  const float* Wih_n = (const float*)d_in[7];
  const float* Whh_n = (const float*)d_in[8];
  const float* bih_n = (const float*)d_in[9];
  const float* bhh_n = (const float*)d_in[10];
  const float* Wih_d = (const float*)d_in[11];
  const float* Whh_d = (const float*)d_in[12];
  const float* bih_d = (const float*)d_in[13];
  const float* bhh_d = (const float*)d_in[14];
  const float* Wpos  = (const float*)d_in[15];
  const float* bpos  = (const float*)d_in[16];
  float* out = (float*)d_out;
  float* wsf = (float*)d_ws;

  prep_kernel<<<96, 256, 0, stream>>>(Whh_a, Whh_n, Wih_d, Whh_d, bih_d, bhh_d,
                                      (uint4*)(wsf + OFF_PACKA),
                                      (uint4*)(wsf + OFF_PACKN),
                                      (uint4*)(wsf + OFF_WDP), wsf + OFF_WDB);
  enc_mfma_kernel<<<2176, 256, 0, stream>>>(
      xA, xN,
      (const v8s*)(wsf + OFF_PACKA), (const v8s*)(wsf + OFF_PACKN),
      Wih_a, bih_a, bhh_a, Wih_n, bih_n, bhh_n,
      wsf + OFF_AEMB, wsf + OFF_NENC);
  dec_mfma_kernel<<<256, 512, 0, stream>>>((const v8s*)(wsf + OFF_WDP),
                                           wsf + OFF_WDB, wsf + OFF_AEMB,
                                           wsf + OFF_NENC, cnts,
                                           Wpos, bpos, out);
}